// Round 1
// baseline (82.452 us; speedup 1.0000x reference)
//
#include <hip/hip_runtime.h>

// QuantumKernelLayer: out[b,c] = | prod_j cos(0.5*(x[b,j] - centers[c,j])) |
// B=8192, C=2048, N=8 (fp32 in, fp32 out).
//
// Strategy: cos((x-c)/2) = cos(x/2)cos(c/2) + sin(x/2)sin(c/2)  (exact identity)
//  -> transcendentals only in the prologue; inner loop is pure FMA.
// Tile: block = 256 threads handles 16 batch rows x 1024 centers.
//   - x-row cos/sin staged in LDS (16*8 float2 = 2 KiB), broadcast reads.
//   - each thread holds cos/sin of its 4 centers in registers (64 VGPRs).
//   - float4 coalesced stores, consecutive threads -> consecutive centers.

#define TPB  256
#define ROWS 16      // batch rows per block
#define CPT  4       // centers per thread
#define NW   8       // wires (inner dim)

__global__ __launch_bounds__(TPB) void quantum_fidelity_kernel(
    const float* __restrict__ x,        // [B, 8]
    const float* __restrict__ centers,  // [C, 8]
    float* __restrict__ out,            // [B, C]
    int C) {
  __shared__ float2 xs[ROWS * NW];  // (cos, sin) of x/2 for this block's rows

  const int t = threadIdx.x;
  const int row0 = blockIdx.y * ROWS;
  const int c0 = (blockIdx.x * TPB + t) * CPT;

  // Stage cos/sin of the 16 rows' x values (128 elements) into LDS.
  if (t < ROWS * NW) {
    float h = 0.5f * x[(size_t)row0 * NW + t];
    xs[t] = make_float2(__cosf(h), __sinf(h));
  }

  // Each thread: cos/sin of its 4 centers (contiguous 128 B -> two float4 each).
  float cc[CPT][NW], sc[CPT][NW];
  const float4* cp = reinterpret_cast<const float4*>(centers + (size_t)c0 * NW);
#pragma unroll
  for (int i = 0; i < CPT; ++i) {
    float4 a = cp[i * 2 + 0];
    float4 b = cp[i * 2 + 1];
    float v[NW] = {a.x, a.y, a.z, a.w, b.x, b.y, b.z, b.w};
#pragma unroll
    for (int j = 0; j < NW; ++j) {
      float h = 0.5f * v[j];
      cc[i][j] = __cosf(h);
      sc[i][j] = __sinf(h);
    }
  }
  __syncthreads();

#pragma unroll 1
  for (int r = 0; r < ROWS; ++r) {
    float2 xv[NW];
#pragma unroll
    for (int j = 0; j < NW; ++j) xv[j] = xs[r * NW + j];  // LDS broadcast

    float pr[CPT];
#pragma unroll
    for (int i = 0; i < CPT; ++i) {
      // prod_j ( cc*cx + sc*sx )
      float p = fmaf(sc[i][0], xv[0].y, cc[i][0] * xv[0].x);
#pragma unroll
      for (int j = 1; j < NW; ++j)
        p *= fmaf(sc[i][j], xv[j].y, cc[i][j] * xv[j].x);
      pr[i] = fabsf(p);
    }
    float4 o = make_float4(pr[0], pr[1], pr[2], pr[3]);
    *reinterpret_cast<float4*>(out + (size_t)(row0 + r) * C + c0) = o;
  }
}

extern "C" void kernel_launch(void* const* d_in, const int* in_sizes, int n_in,
                              void* d_out, int out_size, void* d_ws, size_t ws_size,
                              hipStream_t stream) {
  const float* x = (const float*)d_in[0];
  const float* centers = (const float*)d_in[1];
  float* out = (float*)d_out;

  const int B = in_sizes[0] / NW;  // 8192
  const int C = in_sizes[1] / NW;  // 2048

  dim3 grid(C / (TPB * CPT), B / ROWS);  // (2, 512)
  quantum_fidelity_kernel<<<grid, TPB, 0, stream>>>(x, centers, out, C);
}